// Round 9
// baseline (243.254 us; speedup 1.0000x reference)
//
#include <hip/hip_runtime.h>
#include <hip/hip_bf16.h>
#include <math.h>

#define N_SEQ 4096
#define DIM   1024
#define NHEAD 16
#define HDIM  64
#define E3    3072

typedef short bf16x8 __attribute__((ext_vector_type(8)));
typedef float f32x4  __attribute__((ext_vector_type(4)));
typedef unsigned int u32;

__device__ __forceinline__ float bf2f(unsigned short u) {
    union { unsigned int i; float f; } x; x.i = ((unsigned int)u) << 16; return x.f;
}
__device__ __forceinline__ unsigned short f2bf(float f) {
    union { float f; unsigned int i; } x; x.f = f;
    unsigned int r = x.i + 0x7FFF + ((x.i >> 16) & 1);   // round-to-nearest-even
    return (unsigned short)(r >> 16);
}
// cheap pack for non-negative hot-loop values (round-half-up, 2 VALU ops)
__device__ __forceinline__ unsigned short f2bf_fast(float f) {
    union { float f; unsigned int i; } x; x.f = f;
    return (unsigned short)((x.i + 0x8000u) >> 16);
}
__device__ __forceinline__ f32x4 mfma16(bf16x8 a, bf16x8 b, f32x4 c) {
    return __builtin_amdgcn_mfma_f32_16x16x32_bf16(a, b, c, 0, 0, 0);
}
// async global->LDS, 16B per lane; LDS dest = wave-uniform base + lane*16
__device__ __forceinline__ void gload_lds16(const unsigned short* g, unsigned short* l) {
    __builtin_amdgcn_global_load_lds(
        (const __attribute__((address_space(1))) u32*)g,
        (__attribute__((address_space(3))) u32*)l, 16, 0, 0);
}

// local (per-block) dtype probe: fp32 read as bf16 -> |v|>1e10 or NaN w.p. ~0.37/elem
__device__ __forceinline__ int probe_isf32(const unsigned short* __restrict__ X) {
    __shared__ int cnt;
    if (threadIdx.x == 0) cnt = 0;
    __syncthreads();
    int bad = 0;
    for (int i = threadIdx.x; i < 4096; i += 256) {
        float v = bf2f(X[i]);
        if (!(fabsf(v) < 1e10f)) bad = 1;
    }
    if (bad) atomicAdd(&cnt, 1);
    __syncthreads();
    return cnt > 0;
}

// ---------------------------------------------------------------------------
// Kernel 0: fused prep. Every block locally detects dtype (no cross-block
// dependency); block 0 publishes the flag for downstream kernels. If fp32,
// grid-stride converts {X, Wqkv, Wout} slices to bf16; if bf16, early-exit
// (GEMMs read the original pointers directly, selected by flag).
// ---------------------------------------------------------------------------
__global__ __launch_bounds__(256)
void prep_kernel(const void* __restrict__ X, const void* __restrict__ Wq,
                 const void* __restrict__ Wo,
                 unsigned short* __restrict__ Xb, unsigned short* __restrict__ Wqb,
                 unsigned short* __restrict__ Wob,
                 int* __restrict__ flag)
{
    const int isf32 = probe_isf32((const unsigned short*)X);
    if (blockIdx.x == 0 && threadIdx.x == 0) *flag = isf32;
    if (!isf32) return;

    const int nX4  = (N_SEQ * DIM) >> 2;     // 1Mi vec4
    const int nWq4 = (E3 * DIM) >> 2;        // 768Ki
    const int nWo4 = (DIM * DIM) >> 2;       // 256Ki
    const int total = nX4 + nWq4 + nWo4;
    const int stride = gridDim.x * blockDim.x;
    for (int i = blockIdx.x * blockDim.x + threadIdx.x; i < total; i += stride) {
        const float4* src; ushort4* dst; int j = i;
        if (j < nX4)            { src = (const float4*)X  + j;  dst = (ushort4*)Xb  + j; }
        else if ((j -= nX4) < nWq4) { src = (const float4*)Wq + j;  dst = (ushort4*)Wqb + j; }
        else { j -= nWq4;         src = (const float4*)Wo + j;  dst = (ushort4*)Wob + j; }
        float4 v = *src;
        ushort4 u;
        u.x = f2bf(v.x); u.y = f2bf(v.y); u.z = f2bf(v.z); u.w = f2bf(v.w);
        *dst = u;
    }
}

// ---------------------------------------------------------------------------
// Kernel 1: QKV projection + fused RoPE, frag-layout outputs (proven).
// Source pointers selected by flag (orig bf16 vs converted).
// ---------------------------------------------------------------------------
__global__ __launch_bounds__(256)
void qkv_mfma_kernel(const void* __restrict__ Xo, const unsigned short* __restrict__ Xc,
                     const void* __restrict__ Wo_, const unsigned short* __restrict__ Wc,
                     const int* __restrict__ flag,
                     unsigned short* __restrict__ Qf,
                     unsigned short* __restrict__ Kf,
                     unsigned short* __restrict__ Vf)
{
    __shared__ unsigned short As[128 * 32];   // 8 KB
    __shared__ unsigned short Bs[128 * 32];   // 8 KB

    const int isf32 = *flag;
    const unsigned short* Xb = isf32 ? Xc : (const unsigned short*)Xo;
    const unsigned short* Wb = isf32 ? Wc : (const unsigned short*)Wo_;

    const int tid  = threadIdx.x;
    const int lane = tid & 63;
    const int wave = tid >> 6;
    const int wr = wave >> 1, wc = wave & 1;
    const int lm = lane & 15, q4 = lane >> 4;
    const int rbase = blockIdx.y * 128;   // n
    const int cbase = blockIdx.x * 128;   // e

    const int srow = wave * 16 + (lane >> 2);
    const int scol = (lane & 3) * 8;

    f32x4 acc[4][4];
    #pragma unroll
    for (int i = 0; i < 4; ++i)
        #pragma unroll
        for (int j = 0; j < 4; ++j) acc[i][j] = (f32x4){0.f, 0.f, 0.f, 0.f};

    for (int kt = 0; kt < DIM; kt += 32) {
        #pragma unroll
        for (int j = 0; j < 2; ++j) {
            gload_lds16(Xb + (size_t)(rbase + j*64 + srow) * DIM + kt + scol,
                        &As[j*2048 + wave*512]);
            gload_lds16(Wb + (size_t)(cbase + j*64 + srow) * DIM + kt + scol,
                        &Bs[j*2048 + wave*512]);
        }
        __syncthreads();

        bf16x8 a[4], b[4];
        #pragma unroll
        for (int mi = 0; mi < 4; ++mi)
            a[mi] = *(const bf16x8*)&As[(wr*64 + mi*16 + lm)*32 + q4*8];
        #pragma unroll
        for (int ni = 0; ni < 4; ++ni)
            b[ni] = *(const bf16x8*)&Bs[(wc*64 + ni*16 + lm)*32 + q4*8];
        #pragma unroll
        for (int mi = 0; mi < 4; ++mi)
            #pragma unroll
            for (int ni = 0; ni < 4; ++ni)
                acc[mi][ni] = mfma16(a[mi], b[ni], acc[mi][ni]);

        __syncthreads();
    }

    const int ecol = cbase + wc * 64;
    const int part = ecol >> 10;            // 0=q, 1=k, 2=v
    const int h    = (ecol >> 6) & 15;

    if (part == 2) {
        #pragma unroll
        for (int mi = 0; mi < 4; ++mi)
            #pragma unroll
            for (int r = 0; r < 4; ++r) {
                const int n = rbase + wr*64 + mi*16 + q4*4 + r;   // key
                #pragma unroll
                for (int ni = 0; ni < 4; ++ni) {
                    size_t idx = ((((size_t)h*128 + (n >> 5))*4 + ni) << 9)
                               + ((size_t)(lm | (((n >> 3) & 3) << 4)) << 3) + (n & 7);
                    Vf[idx] = f2bf(acc[mi][ni][r]);
                }
            }
    } else {
        unsigned short* dst = (part == 0) ? Qf : Kf;
        const float scl = (part == 0) ? 0.180336884f : 1.0f;   // log2(e)/8 folded into Q
        const float inv0 = powf(10000.f, -((float)lm)        * (1.f/32.f));
        const float inv1 = powf(10000.f, -((float)(lm + 16)) * (1.f/32.f));
        #pragma unroll
        for (int mi = 0; mi < 4; ++mi)
            #pragma unroll
            for (int r = 0; r < 4; ++r) {
                const int n = rbase + wr*64 + mi*16 + q4*4 + r;
                const size_t tb = ((size_t)(h*256 + (n >> 4))) << 10;
                #pragma unroll
                for (int ni = 0; ni < 2; ++ni) {
                    const int d = ni*16 + lm;                    // < 32
                    float s, c;
                    sincosf((float)n * (ni ? inv1 : inv0), &s, &c);
                    const float vlo = (acc[mi][ni][r]*c - acc[mi][ni+2][r]*s) * scl;
                    const float vhi = (acc[mi][ni+2][r]*c + acc[mi][ni][r]*s) * scl;
                    const size_t idx = tb + ((size_t)((n & 15) | (((d >> 3) & 3) << 4)) << 3) + (d & 7);
                    dst[idx]       = f2bf(vlo);
                    dst[idx + 512] = f2bf(vhi);                  // d+32 lives in chunk 1
                }
            }
    }
}

// ---------------------------------------------------------------------------
// Kernel 2: MFMA flash attention — r8 structure (dbuf K/V staging) +
// BALANCED qb permutation: CU i receives blocks {b, b+256, b+512, b+768}
// (round-robin dispatch); mapping qb = (draw<<4)|(draw odd ? 15-qi : qi)
// makes each CU's four draws sum to exactly 130 tiles.
// ---------------------------------------------------------------------------
__global__ __launch_bounds__(256)
void attn_mfma_kernel(const unsigned short* __restrict__ Qf,
                      const unsigned short* __restrict__ Kf,
                      const unsigned short* __restrict__ Vf,
                      unsigned short* __restrict__ Attn)
{
    __shared__ __align__(16) unsigned short Ks[2][4096];     // 16 KB
    __shared__ __align__(16) unsigned short Vs[2][4096];     // 16 KB
    __shared__ __align__(16) unsigned short P16[4][16][72];  // 9 KB

    const int tid  = threadIdx.x;
    const int lane = tid & 63;
    const int wave = tid >> 6;
    const int q4 = lane >> 4, lm = lane & 15;

    const int h    = blockIdx.x & 15;
    const int w    = blockIdx.x >> 4;          // 0..63
    const int draw = w >> 4;                   // 0..3
    const int qi   = w & 15;
    const int qb   = (draw << 4) | ((draw & 1) ? (15 - qi) : qi);
    const int q0   = qb << 6;
    const int qw   = q0 + (wave << 4);

    const size_t qbase = (((size_t)(h*256 + (qw >> 4))) << 10) + (size_t)lane * 8;
    const bf16x8 aq0 = *(const bf16x8*)(Qf + qbase);
    const bf16x8 aq1 = *(const bf16x8*)(Qf + qbase + 512);

    float l_part[4];
    f32x4 o[4];
    #pragma unroll
    for (int r = 0; r < 4; ++r) l_part[r] = 0.f;
    #pragma unroll
    for (int dc = 0; dc < 4; ++dc) o[dc] = (f32x4){0.f, 0.f, 0.f, 0.f};

    unsigned short* pw = &P16[wave][0][0];
    const int ntiles = (q0 >> 6) + 1;          // identical for all 4 waves

    #define STAGE(buf, kt_)                                                        \
        {                                                                          \
            const size_t ktile = ((size_t)(h*256 + ((kt_) >> 4))) << 10;           \
            const size_t vtile = ((size_t)(h*128 + ((kt_) >> 5))) << 11;           \
            if (wave < 2) {                                                        \
                _Pragma("unroll")                                                  \
                for (int i = 0; i < 4; ++i) {                                      \
                    const int ch = wave*4 + i;                                     \
                    gload_lds16(Kf + ktile + ch*512 + lane*8, &Ks[buf][ch*512]);   \
                }                                                                  \
            } else {                                                               \
                _Pragma("unroll")                                                  \
                for (int i = 0; i < 4; ++i) {                                      \
                    const int ch = (wave - 2)*4 + i;                               \
                    gload_lds16(Vf + vtile + ch*512 + lane*8, &Vs[buf][ch*512]);   \
                }                                                                  \
            }                                                                      \
        }

    STAGE(0, 0)

    for (int it = 0; it < ntiles; ++it) {
        const int kt = it << 6;
        const int cur = it & 1;

        __syncthreads();   // waits this tile's staging + buffer reuse safety
        if (it + 1 < ntiles) STAGE(cur ^ 1, kt + 64)

        // ---- S = Q K^T for 64 keys ----
        f32x4 s[4];
        #pragma unroll
        for (int t = 0; t < 4; ++t) {
            const bf16x8 bk0 = *(const bf16x8*)&Ks[cur][t*1024 + lane*8];
            const bf16x8 bk1 = *(const bf16x8*)&Ks[cur][t*1024 + 512 + lane*8];
            f32x4 z = (f32x4){0.f, 0.f, 0.f, 0.f};
            z = mfma16(aq0, bk0, z);
            s[t] = mfma16(aq1, bk1, z);
        }

        // ---- causal mask (diagonal tile only) ----
        if (kt + 63 > qw) {
            #pragma unroll
            for (int t = 0; t < 4; ++t) {
                const int key = kt + 16*t + lm;
                #pragma unroll
                for (int r = 0; r < 4; ++r)
                    if (key > qw + 4*q4 + r) s[t][r] = -INFINITY;
            }
        }

        // ---- unnormalized softmax: p = exp2(s); accumulate per-lane l ----
        #pragma unroll
        for (int t = 0; t < 4; ++t)
            #pragma unroll
            for (int r = 0; r < 4; ++r) {
                const float p = exp2f(s[t][r]);
                l_part[r] += p;
                pw[(4*q4 + r)*72 + 16*t + lm] = f2bf_fast(p);
            }

        const bf16x8 pa0 = *(const bf16x8*)(pw + lm*72 + 8*q4);
        const bf16x8 pa1 = *(const bf16x8*)(pw + lm*72 + 32 + 8*q4);

        // ---- O += P V ----
        #pragma unroll
        for (int dc = 0; dc < 4; ++dc) {
            const bf16x8 bv0 = *(const bf16x8*)&Vs[cur][dc*512 + lane*8];
            const bf16x8 bv1 = *(const bf16x8*)&Vs[cur][2048 + dc*512 + lane*8];
            o[dc] = mfma16(pa0, bv0, o[dc]);
            o[dc] = mfma16(pa1, bv1, o[dc]);
        }
    }
    #undef STAGE

    // ---- single deferred l reduction ----
    float inv[4];
    #pragma unroll
    for (int r = 0; r < 4; ++r) {
        float l = l_part[r];
        #pragma unroll
        for (int mk = 1; mk <= 8; mk <<= 1) l += __shfl_xor(l, mk);
        inv[r] = 1.f / l;
    }
    #pragma unroll
    for (int dc = 0; dc < 4; ++dc)
        #pragma unroll
        for (int r = 0; r < 4; ++r)
            Attn[(size_t)(qw + 4*q4 + r) * DIM + (h << 6) + 16*dc + lm] = f2bf(o[dc][r] * inv[r]);
}

// ---------------------------------------------------------------------------
// Kernel 3: out projection, MFMA, 128x64 tiles (proven r8).
// ---------------------------------------------------------------------------
__global__ __launch_bounds__(256)
void out_mfma_kernel(const unsigned short* __restrict__ Ab,
                     const void* __restrict__ Wo_, const unsigned short* __restrict__ Wc,
                     const int* __restrict__ flag,
                     void* __restrict__ Out)
{
    __shared__ unsigned short As[128 * 32];   // 8 KB
    __shared__ unsigned short Bs[64 * 32];    // 4 KB

    const int isf32 = *flag;
    const unsigned short* Wb = isf32 ? Wc : (const unsigned short*)Wo_;

    const int tid  = threadIdx.x;
    const int lane = tid & 63;
    const int wave = tid >> 6;
    const int lm = lane & 15, q4 = lane >> 4;
    const int rbase = blockIdx.y * 128;
    const int cbase = blockIdx.x * 64;

    const int srow16 = lane >> 2;
    const int scol = (lane & 3) * 8;

    f32x4 acc[2][4];
    #pragma unroll
    for (int i = 0; i < 2; ++i)
        #pragma unroll
        for (int j = 0; j < 4; ++j) acc[i][j] = (f32x4){0.f, 0.f, 0.f, 0.f};

    for (int kt = 0; kt < DIM; kt += 32) {
        #pragma unroll
        for (int j = 0; j < 2; ++j) {
            const int row = wave*32 + j*16 + srow16;
            gload_lds16(Ab + (size_t)(rbase + row) * DIM + kt + scol,
                        &As[(wave*32 + j*16)*32]);
        }
        {
            const int row = wave*16 + srow16;
            gload_lds16(Wb + (size_t)(cbase + row) * DIM + kt + scol,
                        &Bs[(wave*16)*32]);
        }
        __syncthreads();

        bf16x8 a[2], b[4];
        #pragma unroll
        for (int mi = 0; mi < 2; ++mi)
            a[mi] = *(const bf16x8*)&As[(wave*32 + mi*16 + lm)*32 + q4*8];
        #pragma unroll
        for (int ni = 0; ni < 4; ++ni)
            b[ni] = *(const bf16x8*)&Bs[(ni*16 + lm)*32 + q4*8];
        #pragma unroll
        for (int mi = 0; mi < 2; ++mi)
            #pragma unroll
            for (int ni = 0; ni < 4; ++ni)
                acc[mi][ni] = mfma16(a[mi], b[ni], acc[mi][ni]);

        __syncthreads();
    }

    #pragma unroll
    for (int mi = 0; mi < 2; ++mi)
        #pragma unroll
        for (int r = 0; r < 4; ++r) {
            const size_t n = rbase + wave*32 + mi*16 + q4*4 + r;
            #pragma unroll
            for (int ni = 0; ni < 4; ++ni) {
                const size_t e = cbase + ni*16 + lm;
                const float v = acc[mi][ni][r];
                if (isf32) ((float*)Out)[n * DIM + e] = v;
                else       ((unsigned short*)Out)[n * DIM + e] = f2bf(v);
            }
        }
}

// ---------------------------------------------------------------------------
extern "C" void kernel_launch(void* const* d_in, const int* in_sizes, int n_in,
                              void* d_out, int out_size, void* d_ws, size_t ws_size,
                              hipStream_t stream) {
    const void* X    = d_in[0];
    const void* Wqkv = d_in[1];
    const void* Wout = d_in[2];

    int* flag = (int*)d_ws;
    unsigned short* base = (unsigned short*)((char*)d_ws + 256);
    const size_t nX = (size_t)N_SEQ * DIM;
    const size_t nWq = (size_t)E3 * DIM;
    const size_t nWo = (size_t)DIM * DIM;
    unsigned short* Xb  = base;
    unsigned short* Wqb = Xb + nX;
    unsigned short* Wob = Wqb + nWq;
    unsigned short* Qf  = Wob + nWo;
    unsigned short* Kf  = Qf + nX;
    unsigned short* Vf  = Kf + nX;
    unsigned short* At  = Vf + nX;

    prep_kernel<<<768, 256, 0, stream>>>(X, Wqkv, Wout, Xb, Wqb, Wob, flag);
    qkv_mfma_kernel<<<dim3(E3 / 128, N_SEQ / 128), 256, 0, stream>>>(X, Xb, Wqkv, Wqb, flag, Qf, Kf, Vf);
    attn_mfma_kernel<<<dim3(NHEAD * (N_SEQ / 64)), 256, 0, stream>>>(Qf, Kf, Vf, At);
    out_mfma_kernel<<<dim3(DIM / 64, N_SEQ / 128), 256, 0, stream>>>(At, Wout, Wob, flag, d_out);
}

// Round 10
// 224.762 us; speedup vs baseline: 1.0823x; 1.0823x over previous
//
#include <hip/hip_runtime.h>
#include <hip/hip_bf16.h>
#include <math.h>

#define N_SEQ 4096
#define DIM   1024
#define NHEAD 16
#define HDIM  64
#define E3    3072

typedef short bf16x8 __attribute__((ext_vector_type(8)));
typedef float f32x4  __attribute__((ext_vector_type(4)));
typedef unsigned int u32;

__device__ __forceinline__ float bf2f(unsigned short u) {
    union { unsigned int i; float f; } x; x.i = ((unsigned int)u) << 16; return x.f;
}
__device__ __forceinline__ unsigned short f2bf(float f) {
    union { float f; unsigned int i; } x; x.f = f;
    unsigned int r = x.i + 0x7FFF + ((x.i >> 16) & 1);   // round-to-nearest-even
    return (unsigned short)(r >> 16);
}
// cheap pack for non-negative hot-loop values (round-half-up, 2 VALU ops)
__device__ __forceinline__ unsigned short f2bf_fast(float f) {
    union { float f; unsigned int i; } x; x.f = f;
    return (unsigned short)((x.i + 0x8000u) >> 16);
}
__device__ __forceinline__ f32x4 mfma16(bf16x8 a, bf16x8 b, f32x4 c) {
    return __builtin_amdgcn_mfma_f32_16x16x32_bf16(a, b, c, 0, 0, 0);
}
// async global->LDS, 16B per lane; LDS dest = wave-uniform base + lane*16
__device__ __forceinline__ void gload_lds16(const unsigned short* g, unsigned short* l) {
    __builtin_amdgcn_global_load_lds(
        (const __attribute__((address_space(1))) u32*)g,
        (__attribute__((address_space(3))) u32*)l, 16, 0, 0);
}

// local (per-block) dtype probe
__device__ __forceinline__ int probe_isf32(const unsigned short* __restrict__ X) {
    __shared__ int cnt;
    if (threadIdx.x == 0) cnt = 0;
    __syncthreads();
    int bad = 0;
    for (int i = threadIdx.x; i < 4096; i += 256) {
        float v = bf2f(X[i]);
        if (!(fabsf(v) < 1e10f)) bad = 1;
    }
    if (bad) atomicAdd(&cnt, 1);
    __syncthreads();
    return cnt > 0;
}

// ---------------------------------------------------------------------------
// Kernel 0: fused prep (proven r9): local detect, convert only if fp32.
// ---------------------------------------------------------------------------
__global__ __launch_bounds__(256)
void prep_kernel(const void* __restrict__ X, const void* __restrict__ Wq,
                 const void* __restrict__ Wo,
                 unsigned short* __restrict__ Xb, unsigned short* __restrict__ Wqb,
                 unsigned short* __restrict__ Wob,
                 int* __restrict__ flag)
{
    const int isf32 = probe_isf32((const unsigned short*)X);
    if (blockIdx.x == 0 && threadIdx.x == 0) *flag = isf32;
    if (!isf32) return;

    const int nX4  = (N_SEQ * DIM) >> 2;
    const int nWq4 = (E3 * DIM) >> 2;
    const int nWo4 = (DIM * DIM) >> 2;
    const int total = nX4 + nWq4 + nWo4;
    const int stride = gridDim.x * blockDim.x;
    for (int i = blockIdx.x * blockDim.x + threadIdx.x; i < total; i += stride) {
        const float4* src; ushort4* dst; int j = i;
        if (j < nX4)                { src = (const float4*)X  + j;  dst = (ushort4*)Xb  + j; }
        else if ((j -= nX4) < nWq4) { src = (const float4*)Wq + j;  dst = (ushort4*)Wqb + j; }
        else { j -= nWq4;             src = (const float4*)Wo + j;  dst = (ushort4*)Wob + j; }
        float4 v = *src;
        ushort4 u;
        u.x = f2bf(v.x); u.y = f2bf(v.y); u.z = f2bf(v.z); u.w = f2bf(v.w);
        *dst = u;
    }
}

// ---------------------------------------------------------------------------
// Kernel 1: QKV projection + fused RoPE, frag-layout outputs.
// r9 body + double-buffered staging (1 barrier per k-step) + pointer
// increments instead of per-step index math.
// ---------------------------------------------------------------------------
__global__ __launch_bounds__(256)
void qkv_mfma_kernel(const void* __restrict__ Xo, const unsigned short* __restrict__ Xc,
                     const void* __restrict__ Wo_, const unsigned short* __restrict__ Wc,
                     const int* __restrict__ flag,
                     unsigned short* __restrict__ Qf,
                     unsigned short* __restrict__ Kf,
                     unsigned short* __restrict__ Vf)
{
    __shared__ unsigned short As[2][4096];   // 16 KB
    __shared__ unsigned short Bs[2][4096];   // 16 KB

    const int isf32 = *flag;
    const unsigned short* Xb = isf32 ? Xc : (const unsigned short*)Xo;
    const unsigned short* Wb = isf32 ? Wc : (const unsigned short*)Wo_;

    const int tid  = threadIdx.x;
    const int lane = tid & 63;
    const int wave = tid >> 6;
    const int wr = wave >> 1, wc = wave & 1;
    const int lm = lane & 15, q4 = lane >> 4;
    const int rbase = blockIdx.y * 128;   // n
    const int cbase = blockIdx.x * 128;   // e

    const int srow = wave * 16 + (lane >> 2);
    const int scol = (lane & 3) * 8;

    const unsigned short* xsrc = Xb + (size_t)(rbase + srow) * DIM + scol;
    const unsigned short* wsrc = Wb + (size_t)(cbase + srow) * DIM + scol;
    const int la = (wr*64 + lm)*32 + q4*8;   // LDS read base (A)
    const int lb = (wc*64 + lm)*32 + q4*8;   // LDS read base (B)

    f32x4 acc[4][4];
    #pragma unroll
    for (int i = 0; i < 4; ++i)
        #pragma unroll
        for (int j = 0; j < 4; ++j) acc[i][j] = (f32x4){0.f, 0.f, 0.f, 0.f};

    #define QSTAGE(buf)                                                         \
        {                                                                       \
            _Pragma("unroll")                                                   \
            for (int j = 0; j < 2; ++j) {                                       \
                gload_lds16(xsrc + (size_t)j*64*DIM, &As[buf][j*2048 + wave*512]); \
                gload_lds16(wsrc + (size_t)j*64*DIM, &Bs[buf][j*2048 + wave*512]); \
            }                                                                   \
            xsrc += 32; wsrc += 32;                                             \
        }

    QSTAGE(0)
    for (int it = 0; it < DIM/32; ++it) {
        const int cur = it & 1;
        __syncthreads();
        if (it + 1 < DIM/32) QSTAGE(cur ^ 1)

        bf16x8 a[4], b[4];
        #pragma unroll
        for (int mi = 0; mi < 4; ++mi)
            a[mi] = *(const bf16x8*)&As[cur][la + mi*512];
        #pragma unroll
        for (int ni = 0; ni < 4; ++ni)
            b[ni] = *(const bf16x8*)&Bs[cur][lb + ni*512];
        #pragma unroll
        for (int mi = 0; mi < 4; ++mi)
            #pragma unroll
            for (int ni = 0; ni < 4; ++ni)
                acc[mi][ni] = mfma16(a[mi], b[ni], acc[mi][ni]);
    }
    #undef QSTAGE

    const int ecol = cbase + wc * 64;
    const int part = ecol >> 10;            // 0=q, 1=k, 2=v
    const int h    = (ecol >> 6) & 15;

    if (part == 2) {
        #pragma unroll
        for (int mi = 0; mi < 4; ++mi)
            #pragma unroll
            for (int r = 0; r < 4; ++r) {
                const int n = rbase + wr*64 + mi*16 + q4*4 + r;   // key
                #pragma unroll
                for (int ni = 0; ni < 4; ++ni) {
                    size_t idx = ((((size_t)h*128 + (n >> 5))*4 + ni) << 9)
                               + ((size_t)(lm | (((n >> 3) & 3) << 4)) << 3) + (n & 7);
                    Vf[idx] = f2bf(acc[mi][ni][r]);
                }
            }
    } else {
        unsigned short* dst = (part == 0) ? Qf : Kf;
        const float scl = (part == 0) ? 0.180336884f : 1.0f;   // log2(e)/8 folded into Q
        const float inv0 = powf(10000.f, -((float)lm)        * (1.f/32.f));
        const float inv1 = powf(10000.f, -((float)(lm + 16)) * (1.f/32.f));
        #pragma unroll
        for (int mi = 0; mi < 4; ++mi)
            #pragma unroll
            for (int r = 0; r < 4; ++r) {
                const int n = rbase + wr*64 + mi*16 + q4*4 + r;
                const size_t tb = ((size_t)(h*256 + (n >> 4))) << 10;
                #pragma unroll
                for (int ni = 0; ni < 2; ++ni) {
                    const int d = ni*16 + lm;                    // < 32
                    float s, c;
                    sincosf((float)n * (ni ? inv1 : inv0), &s, &c);
                    const float vlo = (acc[mi][ni][r]*c - acc[mi][ni+2][r]*s) * scl;
                    const float vhi = (acc[mi][ni+2][r]*c + acc[mi][ni][r]*s) * scl;
                    const size_t idx = tb + ((size_t)((n & 15) | (((d >> 3) & 3) << 4)) << 3) + (d & 7);
                    dst[idx]       = f2bf(vlo);
                    dst[idx + 512] = f2bf(vhi);                  // d+32 lives in chunk 1
                }
            }
    }
}

// ---------------------------------------------------------------------------
// Kernel 2: MFMA flash attention — r8 LPT ordering (heavy blocks dispatch
// first, dynamic backfill; do NOT assume block->CU mapping), dbuf K/V
// staging, incrementing tile pointers (K/V head tiles are contiguous:
// +4096 shorts per 64-key tile).
// ---------------------------------------------------------------------------
__global__ __launch_bounds__(256)
void attn_mfma_kernel(const unsigned short* __restrict__ Qf,
                      const unsigned short* __restrict__ Kf,
                      const unsigned short* __restrict__ Vf,
                      unsigned short* __restrict__ Attn)
{
    __shared__ __align__(16) unsigned short Ks[2][4096];     // 16 KB
    __shared__ __align__(16) unsigned short Vs[2][4096];     // 16 KB
    __shared__ __align__(16) unsigned short P16[4][16][72];  // 9 KB

    const int tid  = threadIdx.x;
    const int lane = tid & 63;
    const int wave = tid >> 6;
    const int q4 = lane >> 4, lm = lane & 15;

    const int h  = blockIdx.x & 15;
    const int qb = blockIdx.x >> 4;
    const int q0 = (63 - qb) << 6;             // LPT: heavy blocks first
    const int qw = q0 + (wave << 4);

    const size_t qbase = (((size_t)(h*256 + (qw >> 4))) << 10) + (size_t)lane * 8;
    const bf16x8 aq0 = *(const bf16x8*)(Qf + qbase);
    const bf16x8 aq1 = *(const bf16x8*)(Qf + qbase + 512);

    float l_part[4];
    f32x4 o[4];
    #pragma unroll
    for (int r = 0; r < 4; ++r) l_part[r] = 0.f;
    #pragma unroll
    for (int dc = 0; dc < 4; ++dc) o[dc] = (f32x4){0.f, 0.f, 0.f, 0.f};

    // staging pointers: this wave stages 4 chunks of K (waves 0,1) or V (2,3)
    const unsigned short* sbase;
    unsigned short* db0;
    unsigned short* db1;
    {
        const int ch0 = (wave & 1) * 4;
        const size_t hb = ((size_t)h) << 18;
        sbase = ((wave < 2) ? Kf : Vf) + hb + ch0*512 + (size_t)lane*8;
        db0 = ((wave < 2) ? &Ks[0][0] : &Vs[0][0]) + ch0*512;
        db1 = ((wave < 2) ? &Ks[1][0] : &Vs[1][0]) + ch0*512;
    }
    unsigned short* pw  = &P16[wave][0][0];
    unsigned short* pwa = pw + (4*q4)*72 + lm;     // P write base
    const unsigned short* par = pw + lm*72 + 8*q4; // P read base

    const int ntiles = (q0 >> 6) + 1;              // identical for all 4 waves

    #define STAGE(dst)                                                         \
        {                                                                      \
            _Pragma("unroll")                                                  \
            for (int i = 0; i < 4; ++i)                                        \
                gload_lds16(sbase + i*512, (dst) + i*512);                     \
            sbase += 4096;                                                     \
        }

    STAGE(db0)

    for (int it = 0; it < ntiles; ++it) {
        const int kt = it << 6;
        const int cur = it & 1;

        __syncthreads();   // waits this tile's staging + buffer reuse safety
        if (it + 1 < ntiles) STAGE(cur ? db0 : db1)

        const unsigned short* kc = &Ks[cur][lane*8];
        const unsigned short* vc = &Vs[cur][lane*8];

        // ---- S = Q K^T for 64 keys ----
        f32x4 s[4];
        #pragma unroll
        for (int t = 0; t < 4; ++t) {
            const bf16x8 bk0 = *(const bf16x8*)(kc + t*1024);
            const bf16x8 bk1 = *(const bf16x8*)(kc + t*1024 + 512);
            f32x4 z = (f32x4){0.f, 0.f, 0.f, 0.f};
            z = mfma16(aq0, bk0, z);
            s[t] = mfma16(aq1, bk1, z);
        }

        // ---- causal mask (diagonal tile only) ----
        if (kt + 63 > qw) {
            #pragma unroll
            for (int t = 0; t < 4; ++t) {
                const int key = kt + 16*t + lm;
                #pragma unroll
                for (int r = 0; r < 4; ++r)
                    if (key > qw + 4*q4 + r) s[t][r] = -INFINITY;
            }
        }

        // ---- unnormalized softmax: p = exp2(s); accumulate per-lane l ----
        #pragma unroll
        for (int t = 0; t < 4; ++t)
            #pragma unroll
            for (int r = 0; r < 4; ++r) {
                const float p = exp2f(s[t][r]);
                l_part[r] += p;
                pwa[r*72 + 16*t] = f2bf_fast(p);
            }

        const bf16x8 pa0 = *(const bf16x8*)(par);
        const bf16x8 pa1 = *(const bf16x8*)(par + 32);

        // ---- O += P V ----
        #pragma unroll
        for (int dc = 0; dc < 4; ++dc) {
            const bf16x8 bv0 = *(const bf16x8*)(vc + dc*512);
            const bf16x8 bv1 = *(const bf16x8*)(vc + 2048 + dc*512);
            o[dc] = mfma16(pa0, bv0, o[dc]);
            o[dc] = mfma16(pa1, bv1, o[dc]);
        }
    }
    #undef STAGE

    // ---- single deferred l reduction ----
    float inv[4];
    #pragma unroll
    for (int r = 0; r < 4; ++r) {
        float l = l_part[r];
        #pragma unroll
        for (int mk = 1; mk <= 8; mk <<= 1) l += __shfl_xor(l, mk);
        inv[r] = 1.f / l;
    }
    #pragma unroll
    for (int dc = 0; dc < 4; ++dc)
        #pragma unroll
        for (int r = 0; r < 4; ++r)
            Attn[(size_t)(qw + 4*q4 + r) * DIM + (h << 6) + 16*dc + lm] = f2bf(o[dc][r] * inv[r]);
}

// ---------------------------------------------------------------------------
// Kernel 3: out projection, MFMA, 128x64 tiles + dbuf staging.
// ---------------------------------------------------------------------------
__global__ __launch_bounds__(256)
void out_mfma_kernel(const unsigned short* __restrict__ Ab,
                     const void* __restrict__ Wo_, const unsigned short* __restrict__ Wc,
                     const int* __restrict__ flag,
                     void* __restrict__ Out)
{
    __shared__ unsigned short As[2][4096];   // 16 KB
    __shared__ unsigned short Bs[2][2048];   // 8 KB

    const int isf32 = *flag;
    const unsigned short* Wb = isf32 ? Wc : (const unsigned short*)Wo_;

    const int tid  = threadIdx.x;
    const int lane = tid & 63;
    const int wave = tid >> 6;
    const int lm = lane & 15, q4 = lane >> 4;
    const int rbase = blockIdx.y * 128;
    const int cbase = blockIdx.x * 64;

    const int srow16 = lane >> 2;
    const int scol = (lane & 3) * 8;

    const unsigned short* asrc = Ab + (size_t)(rbase + wave*32 + srow16) * DIM + scol;
    const unsigned short* bsrc = Wb + (size_t)(cbase + wave*16 + srow16) * DIM + scol;
    const int la = (wave*32 + lm)*32 + q4*8;
    const int lb = lm*32 + q4*8;

    f32x4 acc[2][4];
    #pragma unroll
    for (int i = 0; i < 2; ++i)
        #pragma unroll
        for (int j = 0; j < 4; ++j) acc[i][j] = (f32x4){0.f, 0.f, 0.f, 0.f};

    #define OSTAGE(buf)                                                          \
        {                                                                        \
            _Pragma("unroll")                                                    \
            for (int j = 0; j < 2; ++j)                                          \
                gload_lds16(asrc + (size_t)j*16*DIM, &As[buf][(wave*32 + j*16)*32]); \
            gload_lds16(bsrc, &Bs[buf][(wave*16)*32]);                           \
            asrc += 32; bsrc += 32;                                              \
        }

    OSTAGE(0)
    for (int it = 0; it < DIM/32; ++it) {
        const int cur = it & 1;
        __syncthreads();
        if (it + 1 < DIM/32) OSTAGE(cur ^ 1)

        bf16x8 a[2], b[4];
        #pragma unroll
        for (int mi = 0; mi < 2; ++mi)
            a[mi] = *(const bf16x8*)&As[cur][la + mi*512];
        #pragma unroll
        for (int ni = 0; ni < 4; ++ni)
            b[ni] = *(const bf16x8*)&Bs[cur][lb + ni*512];
        #pragma unroll
        for (int mi = 0; mi < 2; ++mi)
            #pragma unroll
            for (int ni = 0; ni < 4; ++ni)
                acc[mi][ni] = mfma16(a[mi], b[ni], acc[mi][ni]);
    }
    #undef OSTAGE

    #pragma unroll
    for (int mi = 0; mi < 2; ++mi)
        #pragma unroll
        for (int r = 0; r < 4; ++r) {
            const size_t n = rbase + wave*32 + mi*16 + q4*4 + r;
            #pragma unroll
            for (int ni = 0; ni < 4; ++ni) {
                const size_t e = cbase + ni*16 + lm;
                const float v = acc[mi][ni][r];
                if (isf32) ((float*)Out)[n * DIM + e] = v;
                else       ((unsigned short*)Out)[n * DIM + e] = f2bf(v);
            }
        }
}

// ---------------------------------------------------------------------------
extern "C" void kernel_launch(void* const* d_in, const int* in_sizes, int n_in,
                              void* d_out, int out_size, void* d_ws, size_t ws_size,
                              hipStream_t stream) {
    const void* X    = d_in[0];
    const void* Wqkv = d_in[1];
    const void* Wout = d_in[2];

    int* flag = (int*)d_ws;
    unsigned short* base = (unsigned short*)((char*)d_ws + 256);
    const size_t nX = (size_t)N_SEQ * DIM;
    const size_t nWq = (size_t)E3 * DIM;
    const size_t nWo = (size_t)DIM * DIM;
    unsigned short* Xb  = base;
    unsigned short* Wqb = Xb + nX;
    unsigned short* Wob = Wqb + nWq;
    unsigned short* Qf  = Wob + nWo;
    unsigned short* Kf  = Qf + nX;
    unsigned short* Vf  = Kf + nX;
    unsigned short* At  = Vf + nX;

    prep_kernel<<<768, 256, 0, stream>>>(X, Wqkv, Wout, Xb, Wqb, Wob, flag);
    qkv_mfma_kernel<<<dim3(E3 / 128, N_SEQ / 128), 256, 0, stream>>>(X, Xb, Wqkv, Wqb, flag, Qf, Kf, Vf);
    attn_mfma_kernel<<<dim3(NHEAD * (N_SEQ / 64)), 256, 0, stream>>>(Qf, Kf, Vf, At);
    out_mfma_kernel<<<dim3(DIM / 64, N_SEQ / 128), 256, 0, stream>>>(At, Wout, Wob, flag, d_out);
}

// Round 11
// 213.761 us; speedup vs baseline: 1.1380x; 1.0515x over previous
//
#include <hip/hip_runtime.h>
#include <hip/hip_bf16.h>
#include <math.h>

#define N_SEQ 4096
#define DIM   1024
#define NHEAD 16
#define HDIM  64
#define E3    3072

typedef short bf16x8 __attribute__((ext_vector_type(8)));
typedef float f32x4  __attribute__((ext_vector_type(4)));
typedef unsigned int u32;

#if __has_builtin(__builtin_amdgcn_exp2f)
#define EXP2(x) __builtin_amdgcn_exp2f(x)   // raw v_exp_f32; exp2(-inf)=0
#else
#define EXP2(x) exp2f(x)
#endif

__device__ __forceinline__ float bf2f(unsigned short u) {
    union { unsigned int i; float f; } x; x.i = ((unsigned int)u) << 16; return x.f;
}
__device__ __forceinline__ unsigned short f2bf(float f) {
    union { float f; unsigned int i; } x; x.f = f;
    unsigned int r = x.i + 0x7FFF + ((x.i >> 16) & 1);   // round-to-nearest-even
    return (unsigned short)(r >> 16);
}
// cheap pack for non-negative hot-loop values (round-half-up, 2 VALU ops)
__device__ __forceinline__ unsigned short f2bf_fast(float f) {
    union { float f; unsigned int i; } x; x.f = f;
    return (unsigned short)((x.i + 0x8000u) >> 16);
}
__device__ __forceinline__ f32x4 mfma16(bf16x8 a, bf16x8 b, f32x4 c) {
    return __builtin_amdgcn_mfma_f32_16x16x32_bf16(a, b, c, 0, 0, 0);
}
// async global->LDS, 16B per lane; LDS dest = wave-uniform base + lane*16
__device__ __forceinline__ void gload_lds16(const unsigned short* g, unsigned short* l) {
    __builtin_amdgcn_global_load_lds(
        (const __attribute__((address_space(1))) u32*)g,
        (__attribute__((address_space(3))) u32*)l, 16, 0, 0);
}

// local (per-block) dtype probe
__device__ __forceinline__ int probe_isf32(const unsigned short* __restrict__ X) {
    __shared__ int cnt;
    if (threadIdx.x == 0) cnt = 0;
    __syncthreads();
    int bad = 0;
    for (int i = threadIdx.x; i < 4096; i += 256) {
        float v = bf2f(X[i]);
        if (!(fabsf(v) < 1e10f)) bad = 1;
    }
    if (bad) atomicAdd(&cnt, 1);
    __syncthreads();
    return cnt > 0;
}

// ---------------------------------------------------------------------------
// Kernel 0: fused prep (proven): local detect, convert only if fp32.
// ---------------------------------------------------------------------------
__global__ __launch_bounds__(256)
void prep_kernel(const void* __restrict__ X, const void* __restrict__ Wq,
                 const void* __restrict__ Wo,
                 unsigned short* __restrict__ Xb, unsigned short* __restrict__ Wqb,
                 unsigned short* __restrict__ Wob,
                 int* __restrict__ flag)
{
    const int isf32 = probe_isf32((const unsigned short*)X);
    if (blockIdx.x == 0 && threadIdx.x == 0) *flag = isf32;
    if (!isf32) return;

    const int nX4  = (N_SEQ * DIM) >> 2;
    const int nWq4 = (E3 * DIM) >> 2;
    const int nWo4 = (DIM * DIM) >> 2;
    const int total = nX4 + nWq4 + nWo4;
    const int stride = gridDim.x * blockDim.x;
    for (int i = blockIdx.x * blockDim.x + threadIdx.x; i < total; i += stride) {
        const float4* src; ushort4* dst; int j = i;
        if (j < nX4)                { src = (const float4*)X  + j;  dst = (ushort4*)Xb  + j; }
        else if ((j -= nX4) < nWq4) { src = (const float4*)Wq + j;  dst = (ushort4*)Wqb + j; }
        else { j -= nWq4;             src = (const float4*)Wo + j;  dst = (ushort4*)Wob + j; }
        float4 v = *src;
        ushort4 u;
        u.x = f2bf(v.x); u.y = f2bf(v.y); u.z = f2bf(v.z); u.w = f2bf(v.w);
        *dst = u;
    }
}

// ---------------------------------------------------------------------------
// Kernel 1: QKV projection + fused RoPE. Main loop = r10 (dbuf, ptr-incr).
// NEW: epilogue transposes C-layout -> frag layout through per-wave LDS
// (reusing the 32 KB staging buffers after one barrier) so global stores
// are coalesced b128 instead of 128 scattered b16 per thread.
// Dest index formulas identical to the r10-proven scatter.
// ---------------------------------------------------------------------------
__global__ __launch_bounds__(256)
void qkv_mfma_kernel(const void* __restrict__ Xo, const unsigned short* __restrict__ Xc,
                     const void* __restrict__ Wo_, const unsigned short* __restrict__ Wc,
                     const int* __restrict__ flag,
                     unsigned short* __restrict__ Qf,
                     unsigned short* __restrict__ Kf,
                     unsigned short* __restrict__ Vf)
{
    __shared__ __align__(16) unsigned short SMEM[4][4096];   // 32 KB: As[2]=SMEM[0,1], Bs[2]=SMEM[2,3]

    const int isf32 = *flag;
    const unsigned short* Xb = isf32 ? Xc : (const unsigned short*)Xo;
    const unsigned short* Wb = isf32 ? Wc : (const unsigned short*)Wo_;

    const int tid  = threadIdx.x;
    const int lane = tid & 63;
    const int wave = tid >> 6;
    const int wr = wave >> 1, wc = wave & 1;
    const int lm = lane & 15, q4 = lane >> 4;
    const int rbase = blockIdx.y * 128;   // n
    const int cbase = blockIdx.x * 128;   // e

    const int srow = wave * 16 + (lane >> 2);
    const int scol = (lane & 3) * 8;

    const unsigned short* xsrc = Xb + (size_t)(rbase + srow) * DIM + scol;
    const unsigned short* wsrc = Wb + (size_t)(cbase + srow) * DIM + scol;
    const int la = (wr*64 + lm)*32 + q4*8;
    const int lb = (wc*64 + lm)*32 + q4*8;

    f32x4 acc[4][4];
    #pragma unroll
    for (int i = 0; i < 4; ++i)
        #pragma unroll
        for (int j = 0; j < 4; ++j) acc[i][j] = (f32x4){0.f, 0.f, 0.f, 0.f};

    #define QSTAGE(buf)                                                             \
        {                                                                           \
            _Pragma("unroll")                                                       \
            for (int j = 0; j < 2; ++j) {                                           \
                gload_lds16(xsrc + (size_t)j*64*DIM, &SMEM[buf][j*2048 + wave*512]);   \
                gload_lds16(wsrc + (size_t)j*64*DIM, &SMEM[2+buf][j*2048 + wave*512]); \
            }                                                                       \
            xsrc += 32; wsrc += 32;                                                 \
        }

    QSTAGE(0)
    for (int it = 0; it < DIM/32; ++it) {
        const int cur = it & 1;
        __syncthreads();
        if (it + 1 < DIM/32) QSTAGE(cur ^ 1)

        bf16x8 a[4], b[4];
        #pragma unroll
        for (int mi = 0; mi < 4; ++mi)
            a[mi] = *(const bf16x8*)&SMEM[cur][la + mi*512];
        #pragma unroll
        for (int ni = 0; ni < 4; ++ni)
            b[ni] = *(const bf16x8*)&SMEM[2+cur][lb + ni*512];
        #pragma unroll
        for (int mi = 0; mi < 4; ++mi)
            #pragma unroll
            for (int ni = 0; ni < 4; ++ni)
                acc[mi][ni] = mfma16(a[mi], b[ni], acc[mi][ni]);
    }
    #undef QSTAGE

    __syncthreads();   // staging LDS now free for epilogue transpose

    const int ecol = cbase + wc * 64;
    const int part = ecol >> 10;            // 0=q, 1=k, 2=v
    const int h    = (ecol >> 6) & 15;
    unsigned short* ep = &SMEM[0][0] + wave*4096;   // 8 KB per-wave region

    if (part == 2) {
        // ---- V: Ls[d][n&31] stride 40, two 32-row halves ----
        #pragma unroll
        for (int mh = 0; mh < 2; ++mh) {
            #pragma unroll
            for (int mi2 = 0; mi2 < 2; ++mi2) {
                const int mi = mh*2 + mi2;
                #pragma unroll
                for (int r = 0; r < 4; ++r) {
                    const int n31 = mi2*16 + q4*4 + r;
                    #pragma unroll
                    for (int ni = 0; ni < 4; ++ni)
                        ep[(ni*16 + lm)*40 + n31] = f2bf(acc[mi][ni][r]);
                }
            }
            const int nb = rbase + wr*64 + mh*32;     // 32-aligned
            const size_t vb = (((size_t)h*128 + (nb >> 5)) << 11) + (size_t)lane*8;
            #pragma unroll
            for (int ni = 0; ni < 4; ++ni) {
                const bf16x8 fr = *(const bf16x8*)(ep + (ni*16 + lm)*40 + q4*8);
                *(bf16x8*)(Vf + vb + (size_t)ni*512) = fr;
            }
        }
    } else {
        // ---- Q/K: RoPE then Ls[n&15][d] stride 72, per-16-row tile ----
        unsigned short* dst = (part == 0) ? Qf : Kf;
        const float scl = (part == 0) ? 0.180336884f : 1.0f;   // log2(e)/8 folded into Q
        const float inv0 = powf(10000.f, -((float)lm)        * (1.f/32.f));
        const float inv1 = powf(10000.f, -((float)(lm + 16)) * (1.f/32.f));
        #pragma unroll
        for (int mi = 0; mi < 4; ++mi) {
            const int tn = rbase + wr*64 + mi*16;     // 16-aligned tile base
            #pragma unroll
            for (int r = 0; r < 4; ++r) {
                const int n = tn + q4*4 + r;
                float s0, c0, s1, c1;
                sincosf((float)n * inv0, &s0, &c0);
                sincosf((float)n * inv1, &s1, &c1);
                const int row = (q4*4 + r)*72;
                ep[row + lm]      = f2bf((acc[mi][0][r]*c0 - acc[mi][2][r]*s0) * scl);
                ep[row + lm + 16] = f2bf((acc[mi][1][r]*c1 - acc[mi][3][r]*s1) * scl);
                ep[row + lm + 32] = f2bf((acc[mi][2][r]*c0 + acc[mi][0][r]*s0) * scl);
                ep[row + lm + 48] = f2bf((acc[mi][3][r]*c1 + acc[mi][1][r]*s1) * scl);
            }
            const size_t tb = (((size_t)(h*256 + (tn >> 4))) << 10) + (size_t)lane*8;
            #pragma unroll
            for (int c = 0; c < 2; ++c) {
                const bf16x8 fr = *(const bf16x8*)(ep + lm*72 + c*32 + q4*8);
                *(bf16x8*)(dst + tb + (size_t)c*512) = fr;
            }
        }
    }
}

// ---------------------------------------------------------------------------
// Kernel 2: MFMA flash attention — r10 structure (LPT order, dbuf staging,
// ptr increments); exp2f replaced by raw v_exp_f32.
// ---------------------------------------------------------------------------
__global__ __launch_bounds__(256)
void attn_mfma_kernel(const unsigned short* __restrict__ Qf,
                      const unsigned short* __restrict__ Kf,
                      const unsigned short* __restrict__ Vf,
                      unsigned short* __restrict__ Attn)
{
    __shared__ __align__(16) unsigned short Ks[2][4096];     // 16 KB
    __shared__ __align__(16) unsigned short Vs[2][4096];     // 16 KB
    __shared__ __align__(16) unsigned short P16[4][16][72];  // 9 KB

    const int tid  = threadIdx.x;
    const int lane = tid & 63;
    const int wave = tid >> 6;
    const int q4 = lane >> 4, lm = lane & 15;

    const int h  = blockIdx.x & 15;
    const int qb = blockIdx.x >> 4;
    const int q0 = (63 - qb) << 6;             // LPT: heavy blocks first
    const int qw = q0 + (wave << 4);

    const size_t qbase = (((size_t)(h*256 + (qw >> 4))) << 10) + (size_t)lane * 8;
    const bf16x8 aq0 = *(const bf16x8*)(Qf + qbase);
    const bf16x8 aq1 = *(const bf16x8*)(Qf + qbase + 512);

    float l_part[4];
    f32x4 o[4];
    #pragma unroll
    for (int r = 0; r < 4; ++r) l_part[r] = 0.f;
    #pragma unroll
    for (int dc = 0; dc < 4; ++dc) o[dc] = (f32x4){0.f, 0.f, 0.f, 0.f};

    const unsigned short* sbase;
    unsigned short* db0;
    unsigned short* db1;
    {
        const int ch0 = (wave & 1) * 4;
        const size_t hb = ((size_t)h) << 18;
        sbase = ((wave < 2) ? Kf : Vf) + hb + ch0*512 + (size_t)lane*8;
        db0 = ((wave < 2) ? &Ks[0][0] : &Vs[0][0]) + ch0*512;
        db1 = ((wave < 2) ? &Ks[1][0] : &Vs[1][0]) + ch0*512;
    }
    unsigned short* pw  = &P16[wave][0][0];
    unsigned short* pwa = pw + (4*q4)*72 + lm;
    const unsigned short* par = pw + lm*72 + 8*q4;

    const int ntiles = (q0 >> 6) + 1;

    #define STAGE(dst)                                                         \
        {                                                                      \
            _Pragma("unroll")                                                  \
            for (int i = 0; i < 4; ++i)                                        \
                gload_lds16(sbase + i*512, (dst) + i*512);                     \
            sbase += 4096;                                                     \
        }

    STAGE(db0)

    for (int it = 0; it < ntiles; ++it) {
        const int kt = it << 6;
        const int cur = it & 1;

        __syncthreads();
        if (it + 1 < ntiles) STAGE(cur ? db0 : db1)

        const unsigned short* kc = &Ks[cur][lane*8];
        const unsigned short* vc = &Vs[cur][lane*8];

        f32x4 s[4];
        #pragma unroll
        for (int t = 0; t < 4; ++t) {
            const bf16x8 bk0 = *(const bf16x8*)(kc + t*1024);
            const bf16x8 bk1 = *(const bf16x8*)(kc + t*1024 + 512);
            f32x4 z = (f32x4){0.f, 0.f, 0.f, 0.f};
            z = mfma16(aq0, bk0, z);
            s[t] = mfma16(aq1, bk1, z);
        }

        if (kt + 63 > qw) {
            #pragma unroll
            for (int t = 0; t < 4; ++t) {
                const int key = kt + 16*t + lm;
                #pragma unroll
                for (int r = 0; r < 4; ++r)
                    if (key > qw + 4*q4 + r) s[t][r] = -INFINITY;
            }
        }

        #pragma unroll
        for (int t = 0; t < 4; ++t)
            #pragma unroll
            for (int r = 0; r < 4; ++r) {
                const float p = EXP2(s[t][r]);
                l_part[r] += p;
                pwa[r*72 + 16*t] = f2bf_fast(p);
            }

        const bf16x8 pa0 = *(const bf16x8*)(par);
        const bf16x8 pa1 = *(const bf16x8*)(par + 32);

        #pragma unroll
        for (int dc = 0; dc < 4; ++dc) {
            const bf16x8 bv0 = *(const bf16x8*)(vc + dc*512);
            const bf16x8 bv1 = *(const bf16x8*)(vc + 2048 + dc*512);
            o[dc] = mfma16(pa0, bv0, o[dc]);
            o[dc] = mfma16(pa1, bv1, o[dc]);
        }
    }
    #undef STAGE

    float inv[4];
    #pragma unroll
    for (int r = 0; r < 4; ++r) {
        float l = l_part[r];
        #pragma unroll
        for (int mk = 1; mk <= 8; mk <<= 1) l += __shfl_xor(l, mk);
        inv[r] = 1.f / l;
    }
    #pragma unroll
    for (int dc = 0; dc < 4; ++dc)
        #pragma unroll
        for (int r = 0; r < 4; ++r)
            Attn[(size_t)(qw + 4*q4 + r) * DIM + (h << 6) + 16*dc + lm] = f2bf(o[dc][r] * inv[r]);
}

// ---------------------------------------------------------------------------
// Kernel 3: out projection, MFMA, 128x64 tiles + dbuf staging (r10).
// ---------------------------------------------------------------------------
__global__ __launch_bounds__(256)
void out_mfma_kernel(const unsigned short* __restrict__ Ab,
                     const void* __restrict__ Wo_, const unsigned short* __restrict__ Wc,
                     const int* __restrict__ flag,
                     void* __restrict__ Out)
{
    __shared__ unsigned short As[2][4096];   // 16 KB
    __shared__ unsigned short Bs[2][2048];   // 8 KB

    const int isf32 = *flag;
    const unsigned short* Wb = isf32 ? Wc : (const unsigned short*)Wo_;

    const int tid  = threadIdx.x;
    const int lane = tid & 63;
    const int wave = tid >> 6;
    const int lm = lane & 15, q4 = lane >> 4;
    const int rbase = blockIdx.y * 128;
    const int cbase = blockIdx.x * 64;

    const int srow16 = lane >> 2;
    const int scol = (lane & 3) * 8;

    const unsigned short* asrc = Ab + (size_t)(rbase + wave*32 + srow16) * DIM + scol;
    const unsigned short* bsrc = Wb + (size_t)(cbase + wave*16 + srow16) * DIM + scol;
    const int la = (wave*32 + lm)*32 + q4*8;
    const int lb = lm*32 + q4*8;

    f32x4 acc[2][4];
    #pragma unroll
    for (int i = 0; i < 2; ++i)
        #pragma unroll
        for (int j = 0; j < 4; ++j) acc[i][j] = (f32x4){0.f, 0.f, 0.f, 0.f};

    #define OSTAGE(buf)                                                          \
        {                                                                        \
            _Pragma("unroll")                                                    \
            for (int j = 0; j < 2; ++j)                                          \
                gload_lds16(asrc + (size_t)j*16*DIM, &As[buf][(wave*32 + j*16)*32]); \
            gload_lds16(bsrc, &Bs[buf][(wave*16)*32]);                           \
            asrc += 32; bsrc += 32;                                              \
        }

    OSTAGE(0)
    for (int it = 0; it < DIM/32; ++it) {
        const int cur = it & 1;
        __syncthreads();
        if (it + 1 < DIM/32) OSTAGE(cur ^ 1)

        bf16x8 a[2], b[4];
        #pragma unroll
        for (int mi = 0; mi < 2; ++mi)
            a[mi] = *(const bf16x8*)&As[cur][la + mi*512];
        #pragma unroll
        for (int ni = 0; ni < 4; ++ni)
            b[ni] = *(const bf16x8*)&Bs[cur][lb + ni*512];
        #pragma unroll
        for (int mi = 0; mi < 2; ++mi)
            #pragma unroll
            for (int ni = 0; ni < 4; ++ni)
                acc[mi][ni] = mfma16(a[mi], b[ni], acc[mi][ni]);
    }
    #undef OSTAGE

    #pragma unroll
    for (int mi = 0; mi < 2; ++mi)
        #pragma unroll
        for (int r = 0; r < 4; ++r) {
            const size_t n = rbase + wave*32 + mi*16 + q4*4 + r;
            #pragma unroll
            for (int ni = 0; ni < 4; ++ni) {
                const size_t e = cbase + ni*16 + lm;
                const float v = acc[mi][ni][r];
                if (isf32) ((float*)Out)[n * DIM + e] = v;
                else       ((unsigned short*)Out)[n * DIM + e] = f2bf(v);
            }
        }
}

// ---------------------------------------------------------------------------
extern "C" void kernel_launch(void* const* d_in, const int* in_sizes, int n_in,
                              void* d_out, int out_size, void* d_ws, size_t ws_size,
                              hipStream_t stream) {
    const void* X    = d_in[0];
    const void* Wqkv = d_in[1];
    const void* Wout = d_in[2];

    int* flag = (int*)d_ws;
    unsigned short* base = (unsigned short*)((char*)d_ws + 256);
    const size_t nX = (size_t)N_SEQ * DIM;
    const size_t nWq = (size_t)E3 * DIM;
    const size_t nWo = (size_t)DIM * DIM;
    unsigned short* Xb  = base;
    unsigned short* Wqb = Xb + nX;
    unsigned short* Wob = Wqb + nWq;
    unsigned short* Qf  = Wob + nWo;
    unsigned short* Kf  = Qf + nX;
    unsigned short* Vf  = Kf + nX;
    unsigned short* At  = Vf + nX;

    prep_kernel<<<768, 256, 0, stream>>>(X, Wqkv, Wout, Xb, Wqb, Wob, flag);
    qkv_mfma_kernel<<<dim3(E3 / 128, N_SEQ / 128), 256, 0, stream>>>(X, Xb, Wqkv, Wqb, flag, Qf, Kf, Vf);
    attn_mfma_kernel<<<dim3(NHEAD * (N_SEQ / 64)), 256, 0, stream>>>(Qf, Kf, Vf, At);
    out_mfma_kernel<<<dim3(DIM / 64, N_SEQ / 128), 256, 0, stream>>>(At, Wout, Wob, flag, d_out);
}

// Round 12
// 208.054 us; speedup vs baseline: 1.1692x; 1.0274x over previous
//
#include <hip/hip_runtime.h>
#include <hip/hip_bf16.h>
#include <math.h>

#define N_SEQ 4096
#define DIM   1024
#define NHEAD 16
#define HDIM  64
#define E3    3072

typedef short bf16x8 __attribute__((ext_vector_type(8)));
typedef float f32x4  __attribute__((ext_vector_type(4)));
typedef unsigned int u32;

#if __has_builtin(__builtin_amdgcn_exp2f)
#define EXP2(x) __builtin_amdgcn_exp2f(x)   // raw v_exp_f32; exp2(-inf)=0
#else
#define EXP2(x) exp2f(x)
#endif

__device__ __forceinline__ float bf2f(unsigned short u) {
    union { unsigned int i; float f; } x; x.i = ((unsigned int)u) << 16; return x.f;
}
__device__ __forceinline__ unsigned short f2bf(float f) {
    union { float f; unsigned int i; } x; x.f = f;
    unsigned int r = x.i + 0x7FFF + ((x.i >> 16) & 1);   // round-to-nearest-even
    return (unsigned short)(r >> 16);
}
// cheap pack for non-negative hot-loop values (round-half-up, 2 VALU ops)
__device__ __forceinline__ unsigned short f2bf_fast(float f) {
    union { float f; unsigned int i; } x; x.f = f;
    return (unsigned short)((x.i + 0x8000u) >> 16);
}
__device__ __forceinline__ f32x4 mfma16(bf16x8 a, bf16x8 b, f32x4 c) {
    return __builtin_amdgcn_mfma_f32_16x16x32_bf16(a, b, c, 0, 0, 0);
}
// async global->LDS, 16B per lane; LDS dest = wave-uniform base + lane*16
__device__ __forceinline__ void gload_lds16(const unsigned short* g, unsigned short* l) {
    __builtin_amdgcn_global_load_lds(
        (const __attribute__((address_space(1))) u32*)g,
        (__attribute__((address_space(3))) u32*)l, 16, 0, 0);
}

// local (per-block) dtype probe
__device__ __forceinline__ int probe_isf32(const unsigned short* __restrict__ X) {
    __shared__ int cnt;
    if (threadIdx.x == 0) cnt = 0;
    __syncthreads();
    int bad = 0;
    for (int i = threadIdx.x; i < 4096; i += 256) {
        float v = bf2f(X[i]);
        if (!(fabsf(v) < 1e10f)) bad = 1;
    }
    if (bad) atomicAdd(&cnt, 1);
    __syncthreads();
    return cnt > 0;
}

// ---------------------------------------------------------------------------
// Kernel 0: fused prep (proven): local detect, convert only if fp32.
// ---------------------------------------------------------------------------
__global__ __launch_bounds__(256)
void prep_kernel(const void* __restrict__ X, const void* __restrict__ Wq,
                 const void* __restrict__ Wo,
                 unsigned short* __restrict__ Xb, unsigned short* __restrict__ Wqb,
                 unsigned short* __restrict__ Wob,
                 int* __restrict__ flag)
{
    const int isf32 = probe_isf32((const unsigned short*)X);
    if (blockIdx.x == 0 && threadIdx.x == 0) *flag = isf32;
    if (!isf32) return;

    const int nX4  = (N_SEQ * DIM) >> 2;
    const int nWq4 = (E3 * DIM) >> 2;
    const int nWo4 = (DIM * DIM) >> 2;
    const int total = nX4 + nWq4 + nWo4;
    const int stride = gridDim.x * blockDim.x;
    for (int i = blockIdx.x * blockDim.x + threadIdx.x; i < total; i += stride) {
        const float4* src; ushort4* dst; int j = i;
        if (j < nX4)                { src = (const float4*)X  + j;  dst = (ushort4*)Xb  + j; }
        else if ((j -= nX4) < nWq4) { src = (const float4*)Wq + j;  dst = (ushort4*)Wqb + j; }
        else { j -= nWq4;             src = (const float4*)Wo + j;  dst = (ushort4*)Wob + j; }
        float4 v = *src;
        ushort4 u;
        u.x = f2bf(v.x); u.y = f2bf(v.y); u.z = f2bf(v.z); u.w = f2bf(v.w);
        *dst = u;
    }
}

// ---------------------------------------------------------------------------
// Kernel 1: QKV projection + fused RoPE (r11-proven: dbuf staging, LDS
// epilogue transpose, coalesced b128 frag stores).
// ---------------------------------------------------------------------------
__global__ __launch_bounds__(256)
void qkv_mfma_kernel(const void* __restrict__ Xo, const unsigned short* __restrict__ Xc,
                     const void* __restrict__ Wo_, const unsigned short* __restrict__ Wc,
                     const int* __restrict__ flag,
                     unsigned short* __restrict__ Qf,
                     unsigned short* __restrict__ Kf,
                     unsigned short* __restrict__ Vf)
{
    __shared__ __align__(16) unsigned short SMEM[4][4096];   // 32 KB

    const int isf32 = *flag;
    const unsigned short* Xb = isf32 ? Xc : (const unsigned short*)Xo;
    const unsigned short* Wb = isf32 ? Wc : (const unsigned short*)Wo_;

    const int tid  = threadIdx.x;
    const int lane = tid & 63;
    const int wave = tid >> 6;
    const int wr = wave >> 1, wc = wave & 1;
    const int lm = lane & 15, q4 = lane >> 4;
    const int rbase = blockIdx.y * 128;   // n
    const int cbase = blockIdx.x * 128;   // e

    const int srow = wave * 16 + (lane >> 2);
    const int scol = (lane & 3) * 8;

    const unsigned short* xsrc = Xb + (size_t)(rbase + srow) * DIM + scol;
    const unsigned short* wsrc = Wb + (size_t)(cbase + srow) * DIM + scol;
    const int la = (wr*64 + lm)*32 + q4*8;
    const int lb = (wc*64 + lm)*32 + q4*8;

    f32x4 acc[4][4];
    #pragma unroll
    for (int i = 0; i < 4; ++i)
        #pragma unroll
        for (int j = 0; j < 4; ++j) acc[i][j] = (f32x4){0.f, 0.f, 0.f, 0.f};

    #define QSTAGE(buf)                                                             \
        {                                                                           \
            _Pragma("unroll")                                                       \
            for (int j = 0; j < 2; ++j) {                                           \
                gload_lds16(xsrc + (size_t)j*64*DIM, &SMEM[buf][j*2048 + wave*512]);   \
                gload_lds16(wsrc + (size_t)j*64*DIM, &SMEM[2+buf][j*2048 + wave*512]); \
            }                                                                       \
            xsrc += 32; wsrc += 32;                                                 \
        }

    QSTAGE(0)
    for (int it = 0; it < DIM/32; ++it) {
        const int cur = it & 1;
        __syncthreads();
        if (it + 1 < DIM/32) QSTAGE(cur ^ 1)

        bf16x8 a[4], b[4];
        #pragma unroll
        for (int mi = 0; mi < 4; ++mi)
            a[mi] = *(const bf16x8*)&SMEM[cur][la + mi*512];
        #pragma unroll
        for (int ni = 0; ni < 4; ++ni)
            b[ni] = *(const bf16x8*)&SMEM[2+cur][lb + ni*512];
        #pragma unroll
        for (int mi = 0; mi < 4; ++mi)
            #pragma unroll
            for (int ni = 0; ni < 4; ++ni)
                acc[mi][ni] = mfma16(a[mi], b[ni], acc[mi][ni]);
    }
    #undef QSTAGE

    __syncthreads();   // staging LDS now free for epilogue transpose

    const int ecol = cbase + wc * 64;
    const int part = ecol >> 10;            // 0=q, 1=k, 2=v
    const int h    = (ecol >> 6) & 15;
    unsigned short* ep = &SMEM[0][0] + wave*4096;

    if (part == 2) {
        #pragma unroll
        for (int mh = 0; mh < 2; ++mh) {
            #pragma unroll
            for (int mi2 = 0; mi2 < 2; ++mi2) {
                const int mi = mh*2 + mi2;
                #pragma unroll
                for (int r = 0; r < 4; ++r) {
                    const int n31 = mi2*16 + q4*4 + r;
                    #pragma unroll
                    for (int ni = 0; ni < 4; ++ni)
                        ep[(ni*16 + lm)*40 + n31] = f2bf(acc[mi][ni][r]);
                }
            }
            const int nb = rbase + wr*64 + mh*32;
            const size_t vb = (((size_t)h*128 + (nb >> 5)) << 11) + (size_t)lane*8;
            #pragma unroll
            for (int ni = 0; ni < 4; ++ni) {
                const bf16x8 fr = *(const bf16x8*)(ep + (ni*16 + lm)*40 + q4*8);
                *(bf16x8*)(Vf + vb + (size_t)ni*512) = fr;
            }
        }
    } else {
        unsigned short* dst = (part == 0) ? Qf : Kf;
        const float scl = (part == 0) ? 0.180336884f : 1.0f;   // log2(e)/8 folded into Q
        const float inv0 = powf(10000.f, -((float)lm)        * (1.f/32.f));
        const float inv1 = powf(10000.f, -((float)(lm + 16)) * (1.f/32.f));
        #pragma unroll
        for (int mi = 0; mi < 4; ++mi) {
            const int tn = rbase + wr*64 + mi*16;
            #pragma unroll
            for (int r = 0; r < 4; ++r) {
                const int n = tn + q4*4 + r;
                float s0, c0, s1, c1;
                sincosf((float)n * inv0, &s0, &c0);
                sincosf((float)n * inv1, &s1, &c1);
                const int row = (q4*4 + r)*72;
                ep[row + lm]      = f2bf((acc[mi][0][r]*c0 - acc[mi][2][r]*s0) * scl);
                ep[row + lm + 16] = f2bf((acc[mi][1][r]*c1 - acc[mi][3][r]*s1) * scl);
                ep[row + lm + 32] = f2bf((acc[mi][2][r]*c0 + acc[mi][0][r]*s0) * scl);
                ep[row + lm + 48] = f2bf((acc[mi][3][r]*c1 + acc[mi][1][r]*s1) * scl);
            }
            const size_t tb = (((size_t)(h*256 + (tn >> 4))) << 10) + (size_t)lane*8;
            #pragma unroll
            for (int c = 0; c < 2; ++c) {
                const bf16x8 fr = *(const bf16x8*)(ep + lm*72 + c*32 + q4*8);
                *(bf16x8*)(dst + tb + (size_t)c*512) = fr;
            }
        }
    }
}

// ---------------------------------------------------------------------------
// Kernel 2: MFMA flash attention — 2x2 wave split (qh = query half,
// kh = key half): each wave computes 32q x 32k per tile and reads only its
// 8 KB of K/V frags from LDS (halves the dominant DS-read traffic).
// O/l reduced across key-half waves once per block via reused staging LDS.
// LPT dispatch order, dbuf staging, ptr increments all frozen from r11.
// ---------------------------------------------------------------------------
__global__ __launch_bounds__(256)
void attn_mfma_kernel(const unsigned short* __restrict__ Qf,
                      const unsigned short* __restrict__ Kf,
                      const unsigned short* __restrict__ Vf,
                      unsigned short* __restrict__ Attn)
{
    __shared__ __align__(16) unsigned short Ks[2][4096];     // 16 KB (reused as Ox)
    __shared__ __align__(16) unsigned short Vs[2][4096];     // 16 KB (reused as Lx)
    __shared__ __align__(16) unsigned short P16[4][32][40];  // 10 KB

    const int tid  = threadIdx.x;
    const int lane = tid & 63;
    const int wave = tid >> 6;
    const int q4 = lane >> 4, lm = lane & 15;
    const int qh = wave >> 1, kh = wave & 1;

    const int h  = blockIdx.x & 15;
    const int qb = blockIdx.x >> 4;
    const int q0 = (63 - qb) << 6;             // LPT: heavy blocks first
    const int qw = q0 + (qh << 5);             // this wave's 32 queries

    // Q A-frags for 32 queries: [qi][d-chunk]
    const unsigned short* qp = Qf + (((size_t)(h*256 + (qw >> 4))) << 10) + (size_t)lane * 8;
    bf16x8 aq[2][2];
    aq[0][0] = *(const bf16x8*)(qp);
    aq[0][1] = *(const bf16x8*)(qp + 512);
    aq[1][0] = *(const bf16x8*)(qp + 1024);
    aq[1][1] = *(const bf16x8*)(qp + 1536);

    float l_part[2][4];
    f32x4 o[2][4];
    #pragma unroll
    for (int qi = 0; qi < 2; ++qi) {
        #pragma unroll
        for (int r = 0; r < 4; ++r) l_part[qi][r] = 0.f;
        #pragma unroll
        for (int dc = 0; dc < 4; ++dc) o[qi][dc] = (f32x4){0.f, 0.f, 0.f, 0.f};
    }

    // staging (unchanged): waves 0,1 stage K chunks 0-3/4-7; waves 2,3 V
    const unsigned short* sbase;
    unsigned short* db0;
    unsigned short* db1;
    {
        const int ch0 = (wave & 1) * 4;
        const size_t hb = ((size_t)h) << 18;
        sbase = ((wave < 2) ? Kf : Vf) + hb + ch0*512 + (size_t)lane*8;
        db0 = ((wave < 2) ? &Ks[0][0] : &Vs[0][0]) + ch0*512;
        db1 = ((wave < 2) ? &Ks[1][0] : &Vs[1][0]) + ch0*512;
    }
    unsigned short* pw  = &P16[wave][0][0];
    unsigned short* pwa = pw + (4*q4)*40 + lm;     // + qi*640 + r*40 + ki*16
    const unsigned short* par = pw + lm*40 + q4*8; // + qi*640

    const int ntiles = (q0 >> 6) + 1;              // identical for all 4 waves

    #define STAGE(dst)                                                         \
        {                                                                      \
            _Pragma("unroll")                                                  \
            for (int i = 0; i < 4; ++i)                                        \
                gload_lds16(sbase + i*512, (dst) + i*512);                     \
            sbase += 4096;                                                     \
        }

    STAGE(db0)

    for (int it = 0; it < ntiles; ++it) {
        const int kt = it << 6;
        const int cur = it & 1;

        __syncthreads();
        if (it + 1 < ntiles) STAGE(cur ? db0 : db1)

        const unsigned short* kc = &Ks[cur][kh*2048 + lane*8];   // this wave's 32 keys
        const unsigned short* vc = &Vs[cur][kh*2048 + lane*8];

        // ---- S = Q K^T : 32 q x 32 k ----
        f32x4 s[2][2];                      // [qi][ki]
        #pragma unroll
        for (int ki = 0; ki < 2; ++ki) {
            const bf16x8 bk0 = *(const bf16x8*)(kc + ki*1024);
            const bf16x8 bk1 = *(const bf16x8*)(kc + ki*1024 + 512);
            #pragma unroll
            for (int qi = 0; qi < 2; ++qi) {
                f32x4 z = (f32x4){0.f, 0.f, 0.f, 0.f};
                z = mfma16(aq[qi][0], bk0, z);
                s[qi][ki] = mfma16(aq[qi][1], bk1, z);
            }
        }

        // ---- causal mask: key = kt+32kh+16ki+lm, query = qw+16qi+4q4+r ----
        if (kt + 32*kh + 31 > qw) {
            #pragma unroll
            for (int ki = 0; ki < 2; ++ki) {
                const int key = kt + 32*kh + 16*ki + lm;
                #pragma unroll
                for (int qi = 0; qi < 2; ++qi) {
                    const int qq = qw + 16*qi + 4*q4;
                    #pragma unroll
                    for (int r = 0; r < 4; ++r)
                        if (key > qq + r) s[qi][ki][r] = -INFINITY;
                }
            }
        }

        // ---- p = exp2(s); per-lane l; P write ----
        #pragma unroll
        for (int qi = 0; qi < 2; ++qi)
            #pragma unroll
            for (int ki = 0; ki < 2; ++ki)
                #pragma unroll
                for (int r = 0; r < 4; ++r) {
                    const float p = EXP2(s[qi][ki][r]);
                    l_part[qi][r] += p;
                    pwa[qi*640 + r*40 + ki*16] = f2bf_fast(p);
                }

        bf16x8 pa[2];
        pa[0] = *(const bf16x8*)(par);
        pa[1] = *(const bf16x8*)(par + 640);

        // ---- O += P V (32 keys per wave) ----
        #pragma unroll
        for (int dc = 0; dc < 4; ++dc) {
            const bf16x8 bv = *(const bf16x8*)(vc + dc*512);
            #pragma unroll
            for (int qi = 0; qi < 2; ++qi)
                o[qi][dc] = mfma16(pa[qi], bv, o[qi][dc]);
        }
    }
    #undef STAGE

    // ---- l reduction over the key axis within the wave (lm groups) ----
    #pragma unroll
    for (int qi = 0; qi < 2; ++qi)
        #pragma unroll
        for (int r = 0; r < 4; ++r) {
            float l = l_part[qi][r];
            #pragma unroll
            for (int mk = 1; mk <= 8; mk <<= 1) l += __shfl_xor(l, mk);
            l_part[qi][r] = l;
        }

    // ---- cross-wave (key-half) reduction via reused staging LDS ----
    float* Ox = (float*)&Ks[0][0];     // [qh][q' 32][d 64] : 4096 floats
    float* Lx = (float*)&Vs[0][0];     // [qh][q' 32]
    __syncthreads();                   // loop done; staging buffers free
    if (kh == 1) {
        #pragma unroll
        for (int qi = 0; qi < 2; ++qi) {
            #pragma unroll
            for (int r = 0; r < 4; ++r) {
                const int qq = 16*qi + 4*q4 + r;
                #pragma unroll
                for (int dc = 0; dc < 4; ++dc)
                    Ox[qh*2048 + qq*64 + 16*dc + lm] = o[qi][dc][r];
                if (lm == 0) Lx[qh*32 + qq] = l_part[qi][r];
            }
        }
    }
    __syncthreads();
    if (kh == 0) {
        #pragma unroll
        for (int qi = 0; qi < 2; ++qi)
            #pragma unroll
            for (int r = 0; r < 4; ++r) {
                const int qq = 16*qi + 4*q4 + r;
                const float inv = 1.f / (l_part[qi][r] + Lx[qh*32 + qq]);
                const size_t row = (size_t)(qw + qq) * DIM + (h << 6) + lm;
                #pragma unroll
                for (int dc = 0; dc < 4; ++dc) {
                    const float v = o[qi][dc][r] + Ox[qh*2048 + qq*64 + 16*dc + lm];
                    Attn[row + 16*dc] = f2bf(v * inv);
                }
            }
    }
}

// ---------------------------------------------------------------------------
// Kernel 3: out projection, MFMA, 128x64 tiles + dbuf staging (r10-proven).
// ---------------------------------------------------------------------------
__global__ __launch_bounds__(256)
void out_mfma_kernel(const unsigned short* __restrict__ Ab,
                     const void* __restrict__ Wo_, const unsigned short* __restrict__ Wc,
                     const int* __restrict__ flag,
                     void* __restrict__ Out)
{
    __shared__ unsigned short As[2][4096];   // 16 KB
    __shared__ unsigned short Bs[2][2048];   // 8 KB

    const int isf32 = *flag;
    const unsigned short* Wb = isf32 ? Wc : (const unsigned short*)Wo_;

    const int tid  = threadIdx.x;
    const int lane = tid & 63;
    const int wave = tid >> 6;
    const int lm = lane & 15, q4 = lane >> 4;
    const int rbase = blockIdx.y * 128;
    const int cbase = blockIdx.x * 64;

    const int srow16 = lane >> 2;
    const int scol = (lane & 3) * 8;

    const unsigned short* asrc = Ab + (size_t)(rbase + wave*32 + srow16) * DIM + scol;
    const unsigned short* bsrc = Wb + (size_t)(cbase + wave*16 + srow16) * DIM + scol;
    const int la = (wave*32 + lm)*32 + q4*8;
    const int lb = lm*32 + q4*8;

    f32x4 acc[2][4];
    #pragma unroll
    for (int i = 0; i < 2; ++i)
        #pragma unroll
        for (int j = 0; j < 4; ++j) acc[i][j] = (f32x4){0.f, 0.f, 0.f, 0.f};

    #define OSTAGE(buf)                                                          \
        {                                                                        \
            _Pragma("unroll")                                                    \
            for (int j = 0; j < 2; ++j)                                          \
                gload_lds16(asrc + (size_t)j*16*DIM, &As[buf][(wave*32 + j*16)*32]); \
            gload_lds16(bsrc, &Bs[buf][(wave*16)*32]);                           \
            asrc += 32; bsrc += 32;                                              \
        }

    OSTAGE(0)
    for (int it = 0; it < DIM/32; ++it) {
        const int cur = it & 1;
        __syncthreads();
        if (it + 1 < DIM/32) OSTAGE(cur ^ 1)

        bf16x8 a[2], b[4];
        #pragma unroll
        for (int mi = 0; mi < 2; ++mi)
            a[mi] = *(const bf16x8*)&As[cur][la + mi*512];
        #pragma unroll
        for (int ni = 0; ni < 4; ++ni)
            b[ni] = *(const bf16x8*)&Bs[cur][lb + ni*512];
        #pragma unroll
        for (int mi = 0; mi < 2; ++mi)
            #pragma unroll
            for (int ni = 0; ni < 4; ++ni)
                acc[mi][ni] = mfma16(a[mi], b[ni], acc[mi][ni]);
    }
    #undef OSTAGE

    #pragma unroll
    for (int mi = 0; mi < 2; ++mi)
        #pragma unroll
        for (int r = 0; r < 4; ++r) {
            const size_t n = rbase + wave*32 + mi*16 + q4*4 + r;
            #pragma unroll
            for (int ni = 0; ni < 4; ++ni) {
                const size_t e = cbase + ni*16 + lm;
                const float v = acc[mi][ni][r];
                if (isf32) ((float*)Out)[n * DIM + e] = v;
                else       ((unsigned short*)Out)[n * DIM + e] = f2bf(v);
            }
        }
}

// ---------------------------------------------------------------------------
extern "C" void kernel_launch(void* const* d_in, const int* in_sizes, int n_in,
                              void* d_out, int out_size, void* d_ws, size_t ws_size,
                              hipStream_t stream) {
    const void* X    = d_in[0];
    const void* Wqkv = d_in[1];
    const void* Wout = d_in[2];

    int* flag = (int*)d_ws;
    unsigned short* base = (unsigned short*)((char*)d_ws + 256);
    const size_t nX = (size_t)N_SEQ * DIM;
    const size_t nWq = (size_t)E3 * DIM;
    const size_t nWo = (size_t)DIM * DIM;
    unsigned short* Xb  = base;
    unsigned short* Wqb = Xb + nX;
    unsigned short* Wob = Wqb + nWq;
    unsigned short* Qf  = Wob + nWo;
    unsigned short* Kf  = Qf + nX;
    unsigned short* Vf  = Kf + nX;
    unsigned short* At  = Vf + nX;

    prep_kernel<<<768, 256, 0, stream>>>(X, Wqkv, Wout, Xb, Wqb, Wob, flag);
    qkv_mfma_kernel<<<dim3(E3 / 128, N_SEQ / 128), 256, 0, stream>>>(X, Xb, Wqkv, Wqb, flag, Qf, Kf, Vf);
    attn_mfma_kernel<<<dim3(NHEAD * (N_SEQ / 64)), 256, 0, stream>>>(Qf, Kf, Vf, At);
    out_mfma_kernel<<<dim3(DIM / 64, N_SEQ / 128), 256, 0, stream>>>(At, Wout, Wob, flag, d_out);
}